// Round 11
// baseline (105.974 us; speedup 1.0000x reference)
//
#include <hip/hip_runtime.h>

typedef __bf16 bf16_t;
typedef bf16_t bf16x8 __attribute__((ext_vector_type(8)));
typedef bf16_t bf16x4 __attribute__((ext_vector_type(4)));
typedef float f32x4 __attribute__((ext_vector_type(4)));

__device__ __forceinline__ void gload_lds16(const bf16_t* g, bf16_t* l) {
    __builtin_amdgcn_global_load_lds(
        (const __attribute__((address_space(1))) void*)g,
        (__attribute__((address_space(3))) void*)l, 16, 0, 0);
}

// ---------------- fp32 -> bf16 convert (both weight matrices, one launch) ----------------
__global__ __launch_bounds__(256) void cvt_bf16_kernel(const float* __restrict__ in1,
                                                       const float* __restrict__ in2,
                                                       bf16_t* __restrict__ out1,
                                                       bf16_t* __restrict__ out2,
                                                       int n1_4, int ntot_4) {
    int i = blockIdx.x * 256 + threadIdx.x;
    if (i >= ntot_4) return;
    const float* in = (i < n1_4) ? in1 : in2;
    bf16_t* out = (i < n1_4) ? out1 : out2;
    int j = (i < n1_4) ? i : i - n1_4;
    float4 v = reinterpret_cast<const float4*>(in)[j];
    bf16x4 o;
    o[0] = (bf16_t)v.x; o[1] = (bf16_t)v.y; o[2] = (bf16_t)v.z; o[3] = (bf16_t)v.w;
    *reinterpret_cast<bf16x4*>(out + (size_t)j * 4) = o;
}

// ---------------- GroupNorm over dim1 groups: single-pass, x register-resident ----------------
__global__ __launch_bounds__(256, 2) void groupnorm_kernel(const float* __restrict__ x,
        const float* __restrict__ gw, const float* __restrict__ gb,
        bf16_t* __restrict__ h) {
    int bg = blockIdx.x;
    int batch = bg >> 5, g = bg & 31;
    const float* xp = x + ((size_t)batch * 1024 + g * 32) * 1024;
    float4 xr[32];
    float s = 0.f, s2 = 0.f;
    #pragma unroll
    for (int i = 0; i < 32; ++i) {
        float4 v = reinterpret_cast<const float4*>(xp)[threadIdx.x + i * 256];
        xr[i] = v;
        s  += v.x + v.y + v.z + v.w;
        s2 += v.x*v.x + v.y*v.y + v.z*v.z + v.w*v.w;
    }
    #pragma unroll
    for (int o = 32; o >= 1; o >>= 1) {
        s  += __shfl_down(s, o, 64);
        s2 += __shfl_down(s2, o, 64);
    }
    __shared__ float ps[4], ps2[4];
    __shared__ float stat[2];
    if ((threadIdx.x & 63) == 0) { ps[threadIdx.x >> 6] = s; ps2[threadIdx.x >> 6] = s2; }
    __syncthreads();
    if (threadIdx.x == 0) {
        float S  = ps[0] + ps[1] + ps[2] + ps[3];
        float S2 = ps2[0] + ps2[1] + ps2[2] + ps2[3];
        float mu  = S * (1.f / 32768.f);
        float var = S2 * (1.f / 32768.f) - mu * mu;
        stat[0] = mu; stat[1] = rsqrtf(var + 1e-6f);
    }
    __syncthreads();
    float mu = stat[0], rs = stat[1];
    bf16_t* hp = h + ((size_t)batch * 1024 + g * 32) * 1024;
    #pragma unroll
    for (int i = 0; i < 32; ++i) {
        int idx = threadIdx.x + i * 256;
        int row = idx >> 8;
        float a = rs * gw[g * 32 + row];
        float b = gb[g * 32 + row] - mu * a;
        float4 v = xr[i];
        bf16x4 o;
        o[0] = (bf16_t)(v.x * a + b); o[1] = (bf16_t)(v.y * a + b);
        o[2] = (bf16_t)(v.z * a + b); o[3] = (bf16_t)(v.w * a + b);
        *reinterpret_cast<bf16x4*>(hp + (size_t)idx * 4) = o;
    }
}

// ---------------- 256x256 m201-schedule bf16 GEMM: C = A @ W^T + bias ----------------
// 512 thr (8 waves, 2M x 4N), BK=64, LDS 128 KiB (2 slot x 2 half).
// Per K-tile: 4 phases {ds_read || stage -> barrier -> setprio 16 MFMA -> barrier}.
// Liveness-derived staging: A-halves consumed at P3, B-halves at P4 =>
//   P1 stages B0,A1(kt+1); P2 stages B1(kt+1); P4 stages A0(kt+2);
// one counted vmcnt(2) per K-tile at P4 (4 stages proven complete, 1 in flight).
// Tail: modulo-wrapped stage indices (slot-consistent, NT even; regions free >=1 barrier).
__global__ __launch_bounds__(512, 2) void gemm256_kernel(
        const bf16_t* __restrict__ A, const bf16_t* __restrict__ W,
        const float* __restrict__ bias, bf16_t* __restrict__ outp,
        int M, int N, int K) {
    __shared__ bf16_t As[2][2][128 * 64];
    __shared__ bf16_t Bs[2][2][128 * 64];
    int nbx = N >> 8;
    int cpx = gridDim.x >> 3;
    int bid = blockIdx.x;
    int tile = (bid & 7) * cpx + (bid >> 3);
    int bx = tile % nbx, by = tile / nbx;
    int m0 = by * 256, n0 = bx * 256;
    int t = threadIdx.x, l = t & 63, wid = t >> 6;
    int lr = l & 15, lg = l >> 4;
    int wm = (wid >> 2) * 128, wn = (wid & 3) * 64;
    int ah = wid >> 2;            // A half this wave reads
    int bh = (wid & 3) >> 1;      // B half this wave reads
    int bnl = wn & 64;            // col base within B half

    int c0 = t, c1 = t + 512;
    int r0 = c0 >> 3, col0 = (((c0 & 7) ^ (r0 & 7)) << 3);
    int r1 = c1 >> 3, col1 = (((c1 & 7) ^ (r1 & 7)) << 3);

    f32x4 acc[8][4] = {};

#define STAGE_A(slot, hf, kt) { \
        const bf16_t* _s = A + (size_t)(m0 + (hf) * 128) * K + (kt) * 64; \
        gload_lds16(_s + (size_t)r0 * K + col0, &As[slot][hf][c0 * 8]); \
        gload_lds16(_s + (size_t)r1 * K + col1, &As[slot][hf][c1 * 8]); }
#define STAGE_B(slot, hf, kt) { \
        const bf16_t* _s = W + (size_t)(n0 + (hf) * 128) * K + (kt) * 64; \
        gload_lds16(_s + (size_t)r0 * K + col0, &Bs[slot][hf][c0 * 8]); \
        gload_lds16(_s + (size_t)r1 * K + col1, &Bs[slot][hf][c1 * 8]); }
#define LOAD_AF(slot, mq) \
        _Pragma("unroll") \
        for (int i = 0; i < 4; ++i) { \
            int row = (mq) * 64 + i * 16 + lr; \
            _Pragma("unroll") \
            for (int kk = 0; kk < 2; ++kk) \
                afr[i][kk] = *reinterpret_cast<const bf16x8*>( \
                    &As[slot][ah][row * 64 + (((kk * 4 + lg) ^ (row & 7)) << 3)]); }
#define LOAD_BF(slot, dst, nq) \
        _Pragma("unroll") \
        for (int j = 0; j < 2; ++j) { \
            int col = bnl + (nq) * 32 + j * 16 + lr; \
            _Pragma("unroll") \
            for (int kk = 0; kk < 2; ++kk) \
                dst[j][kk] = *reinterpret_cast<const bf16x8*>( \
                    &Bs[slot][bh][col * 64 + (((kk * 4 + lg) ^ (col & 7)) << 3)]); }
#define MFMA_Q(mq, nq, bfr) \
        __builtin_amdgcn_s_setprio(1); \
        _Pragma("unroll") \
        for (int i = 0; i < 4; ++i) \
            _Pragma("unroll") \
            for (int j = 0; j < 2; ++j) \
                _Pragma("unroll") \
                for (int kk = 0; kk < 2; ++kk) \
                    acc[(mq) * 4 + i][(nq) * 2 + j] = __builtin_amdgcn_mfma_f32_16x16x32_bf16( \
                        afr[i][kk], bfr[j][kk], acc[(mq) * 4 + i][(nq) * 2 + j], 0, 0, 0); \
        __builtin_amdgcn_s_setprio(0);

    const int NT = K >> 6;   // 16 for K=1024 (even -> wrap keeps slot parity)

    // prologue: tile0 fully + A0(1); first 4 stages complete, 1 in flight
    STAGE_A(0, 0, 0) STAGE_B(0, 0, 0) STAGE_B(0, 1, 0) STAGE_A(0, 1, 0)
    STAGE_A(1, 0, 1)
    asm volatile("s_waitcnt vmcnt(2)" ::: "memory");
    __builtin_amdgcn_s_barrier();

    for (int kt = 0; kt < NT; ++kt) {
        int s = kt & 1, sn = s ^ 1;
        int k1 = (kt + 1) % NT, k2 = (kt + 2) % NT;
        bf16x8 afr[4][2], bf0[2][2], bf1[2][2];
        // P1: read A(mq0), B(nq0); stage B0,A1 of kt+1 (regions free since P4/P3 of kt-1)
        LOAD_AF(s, 0) LOAD_BF(s, bf0, 0)
        STAGE_B(sn, 0, k1)
        STAGE_A(sn, 1, k1)
        __builtin_amdgcn_s_barrier();
        MFMA_Q(0, 0, bf0)
        __builtin_amdgcn_s_barrier();
        // P2: read B(nq1); stage B1 of kt+1
        LOAD_BF(s, bf1, 1)
        STAGE_B(sn, 1, k1)
        __builtin_amdgcn_s_barrier();
        MFMA_Q(0, 1, bf1)
        __builtin_amdgcn_s_barrier();
        // P3: read A(mq1); no stage (A[s] not yet free)
        LOAD_AF(s, 1)
        __builtin_amdgcn_s_barrier();
        MFMA_Q(1, 1, bf1)
        __builtin_amdgcn_s_barrier();
        // P4: re-read B(nq0); stage A0 of kt+2 (A[s] half0 free since P3)
        LOAD_BF(s, bf0, 0)
        STAGE_A(s, 0, k2)
        __builtin_amdgcn_s_barrier();
        MFMA_Q(1, 0, bf0)
        asm volatile("s_waitcnt vmcnt(2)" ::: "memory");   // all of kt+1 landed
        __builtin_amdgcn_s_barrier();
    }

    #pragma unroll
    for (int mf = 0; mf < 8; ++mf) {
        #pragma unroll
        for (int r = 0; r < 4; ++r) {
            int row = m0 + wm + mf * 16 + lg * 4 + r;
            #pragma unroll
            for (int nf = 0; nf < 4; ++nf) {
                int col = n0 + wn + nf * 16 + lr;
                outp[(size_t)row * N + col] = (bf16_t)(acc[mf][nf][r] + bias[col]);
            }
        }
    }
#undef STAGE_A
#undef STAGE_B
#undef LOAD_AF
#undef LOAD_BF
#undef MFMA_Q
}

// ---------------- bf16 MFMA GEMM (m97 structure) with lda: C = A @ W^T (+bias[,+resid]) ----------------
template <int EPI, int BM>
__global__ __launch_bounds__(256) void gemm_nt_kernel(
        const bf16_t* __restrict__ A, const bf16_t* __restrict__ W,
        const float* __restrict__ bias, void* __restrict__ outp,
        const float* __restrict__ resid, int M, int N, int K, int lda) {
    constexpr int MF = BM / 32;
    __shared__ bf16_t As[BM * 64];
    __shared__ bf16_t Bs[128 * 64];
    int nbx = N >> 7;
    int cpx = gridDim.x >> 3;
    int bid = blockIdx.x;
    int tile = (bid & 7) * cpx + (bid >> 3);
    int bx = tile % nbx, by = tile / nbx;
    int m0 = by * BM, n0 = bx * 128;
    int t = threadIdx.x, l = t & 63, wid = t >> 6;
    int wm = (wid >> 1) * (BM / 2), wn = (wid & 1) * 64;
    int lr = l & 15, lg = l >> 4;

    f32x4 acc[MF][4] = {};
    for (int k0 = 0; k0 < K; k0 += 64) {
        #pragma unroll
        for (int i = 0; i < BM / 32; ++i) {
            int c = t + i * 256;
            int row = c >> 3, cc = c & 7;
            int col = (cc ^ (row & 7)) << 3;
            gload_lds16(A + (size_t)(m0 + row) * lda + k0 + col, &As[c * 8]);
        }
        #pragma unroll
        for (int i = 0; i < 4; ++i) {
            int c = t + i * 256;
            int row = c >> 3, cc = c & 7;
            int col = (cc ^ (row & 7)) << 3;
            gload_lds16(W + (size_t)(n0 + row) * K + k0 + col, &Bs[c * 8]);
        }
        __syncthreads();
        #pragma unroll
        for (int s = 0; s < 2; ++s) {
            int xo = ((s * 4 + lg) ^ (lr & 7)) << 3;
            bf16x8 af[MF], bfr[4];
            #pragma unroll
            for (int mf = 0; mf < MF; ++mf)
                af[mf] = *reinterpret_cast<const bf16x8*>(&As[(wm + mf * 16 + lr) * 64 + xo]);
            #pragma unroll
            for (int nf = 0; nf < 4; ++nf)
                bfr[nf] = *reinterpret_cast<const bf16x8*>(&Bs[(wn + nf * 16 + lr) * 64 + xo]);
            #pragma unroll
            for (int mf = 0; mf < MF; ++mf) {
                #pragma unroll
                for (int nf = 0; nf < 4; ++nf)
                    acc[mf][nf] = __builtin_amdgcn_mfma_f32_16x16x32_bf16(af[mf], bfr[nf], acc[mf][nf], 0, 0, 0);
            }
        }
        __syncthreads();
    }
    #pragma unroll
    for (int mf = 0; mf < MF; ++mf) {
        #pragma unroll
        for (int r = 0; r < 4; ++r) {
            int row = m0 + wm + mf * 16 + lg * 4 + r;
            #pragma unroll
            for (int nf = 0; nf < 4; ++nf) {
                int col = n0 + wn + nf * 16 + lr;
                float v = acc[mf][nf][r] + bias[col];
                if (EPI == 0) {
                    reinterpret_cast<bf16_t*>(outp)[(size_t)row * N + col] = (bf16_t)v;
                } else {
                    size_t idx = (size_t)row * N + col;
                    reinterpret_cast<float*>(outp)[idx] = v + resid[idx];
                }
            }
        }
    }
}

// ---------------- fragment prep: K/V of qkv -> MFMA-fragment-ordered buffers ----------------
__global__ __launch_bounds__(256) void frag_prep_kernel(const bf16_t* __restrict__ qkv,
                                                        bf16_t* __restrict__ kfrag,
                                                        bf16_t* __restrict__ vfrag) {
    __shared__ bf16_t vt[32 * 72];
    int t = threadIdx.x;
    int kt = blockIdx.x & 31, bh = blockIdx.x >> 5;
    int b = bh >> 4, hh = bh & 15;
    const bf16_t* kbase = qkv + ((size_t)b * 1024 + kt * 32) * 3072 + 1024 + hh * 64;
    const bf16_t* vbase = kbase + 1024;
    {
        int row = t >> 3, c = t & 7;
        bf16x8 v = *reinterpret_cast<const bf16x8*>(vbase + (size_t)row * 3072 + c * 8);
        *reinterpret_cast<bf16x8*>(&vt[row * 72 + c * 8]) = v;
    }
    {
        int f = (t >> 7) & 1, m = (t >> 6) & 1, l = t & 63;
        bf16x8 v = *reinterpret_cast<const bf16x8*>(
            kbase + (size_t)(f * 16 + (l & 15)) * 3072 + m * 32 + ((l >> 4) & 3) * 8);
        *reinterpret_cast<bf16x8*>(kfrag + ((size_t)bh * 32 + kt) * 2048 + t * 8) = v;
    }
    __syncthreads();
    {
        int nf = (t >> 6) & 3, l = t & 63;
        int d = nf * 16 + (l & 15);
        int lg = (l >> 4) & 3;
        bf16x8 o;
        #pragma unroll
        for (int j = 0; j < 8; ++j) {
            int kpos = lg * 8 + j;
            int kl = ((kpos & 4) << 2) | ((kpos & 24) >> 1) | (kpos & 3);
            o[j] = vt[kl * 72 + d];
        }
        *reinterpret_cast<bf16x8*>(vfrag + ((size_t)bh * 32 + kt) * 2048 + t * 8) = o;
    }
}

// ---------------- flash attention, v9 (verified ~16us): fragment-resident + lockstep L1 ----------------
__global__ __launch_bounds__(256, 2) void attn_kernel(const bf16_t* __restrict__ qkv,
                                                      const bf16_t* __restrict__ kfrag,
                                                      const bf16_t* __restrict__ vfrag,
                                                      bf16_t* __restrict__ oq) {
    int bid = blockIdx.x;
    int tile = (bid & 7) * 64 + (bid >> 3);
    int qt = tile & 7, bh = tile >> 3;
    int hh = bh & 15, bb = bh >> 4;
    int t = threadIdx.x, l = t & 63, wid = t >> 6;
    int lr = l & 15, lg = (l >> 4) & 3;

    bf16x8 qf[2][2];
    #pragma unroll
    for (int s = 0; s < 2; ++s) {
        int qrow = qt * 128 + wid * 32 + s * 16 + lr;
        const bf16_t* qp = qkv + ((size_t)bb * 1024 + qrow) * 3072 + hh * 64;
        bf16x8 q0 = *reinterpret_cast<const bf16x8*>(qp + lg * 8);
        bf16x8 q1 = *reinterpret_cast<const bf16x8*>(qp + 32 + lg * 8);
        #pragma unroll
        for (int j = 0; j < 8; ++j) {
            qf[s][0][j] = (bf16_t)((float)q0[j] * 0.02254211001f);
            qf[s][1][j] = (bf16_t)((float)q1[j] * 0.02254211001f);
        }
    }

    const bf16_t* kfb = kfrag + (size_t)bh * 65536 + l * 8;
    const bf16_t* vfb = vfrag + (size_t)bh * 65536 + l * 8;

    f32x4 acc[2][4] = {};
    float den0 = 0.f, den1 = 0.f;

    bf16x8 kA[4], vA[4], kB[4], vB[4];

#define LOADSET(kS, vS, tt) { \
        const bf16_t* _k = kfb + (tt) * 2048; \
        const bf16_t* _v = vfb + (tt) * 2048; \
        kS[0] = *reinterpret_cast<const bf16x8*>(_k); \
        kS[1] = *reinterpret_cast<const bf16x8*>(_k + 512); \
        kS[2] = *reinterpret_cast<const bf16x8*>(_k + 1024); \
        kS[3] = *reinterpret_cast<const bf16x8*>(_k + 1536); \
        vS[0] = *reinterpret_cast<const bf16x8*>(_v); \
        vS[1] = *reinterpret_cast<const bf16x8*>(_v + 512); \
        vS[2] = *reinterpret_cast<const bf16x8*>(_v + 1024); \
        vS[3] = *reinterpret_cast<const bf16x8*>(_v + 1536); }

#define EX(x) __builtin_amdgcn_exp2f(x)

#define COMPUTE(kS, vS) { \
        f32x4 z00 = {0.f,0.f,0.f,0.f}, z01 = {0.f,0.f,0.f,0.f}; \
        f32x4 z10 = {0.f,0.f,0.f,0.f}, z11 = {0.f,0.f,0.f,0.f}; \
        z00 = __builtin_amdgcn_mfma_f32_16x16x32_bf16(kS[0], qf[0][0], z00, 0, 0, 0); \
        z10 = __builtin_amdgcn_mfma_f32_16x16x32_bf16(kS[0], qf[1][0], z10, 0, 0, 0); \
        z01 = __builtin_amdgcn_mfma_f32_16x16x32_bf16(kS[2], qf[0][0], z01, 0, 0, 0); \
        z11 = __builtin_amdgcn_mfma_f32_16x16x32_bf16(kS[2], qf[1][0], z11, 0, 0, 0); \
        z00 = __builtin_amdgcn_mfma_f32_16x16x32_bf16(kS[1], qf[0][1], z00, 0, 0, 0); \
        z10 = __builtin_amdgcn_mfma_f32_16x16x32_bf16(kS[1], qf[1][1], z10, 0, 0, 0); \
        z01 = __builtin_amdgcn_mfma_f32_16x16x32_bf16(kS[3], qf[0][1], z01, 0, 0, 0); \
        z11 = __builtin_amdgcn_mfma_f32_16x16x32_bf16(kS[3], qf[1][1], z11, 0, 0, 0); \
        float a0 = EX(z00[0]), a1 = EX(z00[1]), a2 = EX(z00[2]), a3 = EX(z00[3]); \
        float a4 = EX(z01[0]), a5 = EX(z01[1]), a6 = EX(z01[2]), a7 = EX(z01[3]); \
        float b0 = EX(z10[0]), b1 = EX(z10[1]), b2 = EX(z10[2]), b3 = EX(z10[3]); \
        float b4 = EX(z11[0]), b5 = EX(z11[1]), b6 = EX(z11[2]), b7 = EX(z11[3]); \
        den0 += ((a0 + a1) + (a2 + a3)) + ((a4 + a5) + (a6 + a7)); \
        den1 += ((b0 + b1) + (b2 + b3)) + ((b4 + b5) + (b6 + b7)); \
        bf16x8 pa0, pa1; \
        pa0[0] = (bf16_t)a0; pa0[1] = (bf16_t)a1; pa0[2] = (bf16_t)a2; pa0[3] = (bf16_t)a3; \
        pa0[4] = (bf16_t)a4; pa0[5] = (bf16_t)a5; pa0[6] = (bf16_t)a6; pa0[7] = (bf16_t)a7; \
        pa1[0] = (bf16_t)b0; pa1[1] = (bf16_t)b1; pa1[2] = (bf16_t)b2; pa1[3] = (bf16_t)b3; \
        pa1[4] = (bf16_t)b4; pa1[5] = (bf16_t)b5; pa1[6] = (bf16_t)b6; pa1[7] = (bf16_t)b7; \
        acc[0][0] = __builtin_amdgcn_mfma_f32_16x16x32_bf16(pa0, vS[0], acc[0][0], 0, 0, 0); \
        acc[0][1] = __builtin_amdgcn_mfma_f32_16x16x32_bf16(pa0, vS[1], acc[0][1], 0, 0, 0); \
        acc[0][2] = __builtin_amdgcn_mfma_f32_16x16x32_bf16(pa0, vS[2], acc[0][2], 0, 0, 0); \
        acc[0][3] = __builtin_amdgcn_mfma_f32_16x16x32_bf16(pa0, vS[3], acc[0][3], 0, 0, 0); \
        acc[1][0] = __builtin_amdgcn_mfma_f32_16x16x32_bf16(pa1, vS[0], acc[1][0], 0, 0, 0); \
        acc[1][1] = __builtin_amdgcn_mfma_f32_16x16x32_bf16(pa1, vS[1], acc[1][1], 0, 0, 0); \
        acc[1][2] = __builtin_amdgcn_mfma_f32_16x16x32_bf16(pa1, vS[2], acc[1][2], 0, 0, 0); \
        acc[1][3] = __builtin_amdgcn_mfma_f32_16x16x32_bf16(pa1, vS[3], acc[1][3], 0, 0, 0); }

    LOADSET(kA, vA, 0)
    for (int kt = 0; kt < 32; kt += 2) {
        __builtin_amdgcn_s_barrier();   // lockstep -> L1 serves 3/4 of frag reads
        LOADSET(kB, vB, kt + 1)
        COMPUTE(kA, vA)
        if (kt + 2 < 32) LOADSET(kA, vA, kt + 2)
        COMPUTE(kB, vB)
    }
#undef LOADSET
#undef COMPUTE
#undef EX

    float rs0[4], rs1[4];
    {
        float v0 = den0, v1 = den1;
        v0 += __shfl_xor(v0, 16, 64);
        v0 += __shfl_xor(v0, 32, 64);
        v1 += __shfl_xor(v1, 16, 64);
        v1 += __shfl_xor(v1, 32, 64);
        #pragma unroll
        for (int r = 0; r < 4; ++r) {
            rs0[r] = 1.f / __shfl(v0, (l & 48) | (lg * 4 + r), 64);
            rs1[r] = 1.f / __shfl(v1, (l & 48) | (lg * 4 + r), 64);
        }
    }

    size_t obase = ((size_t)bh * 1024 + qt * 128 + wid * 32) * 64;
    #pragma unroll
    for (int s = 0; s < 2; ++s) {
        #pragma unroll
        for (int nf = 0; nf < 4; ++nf) {
            #pragma unroll
            for (int r = 0; r < 4; ++r) {
                int q = s * 16 + lg * 4 + r;
                int d = nf * 16 + lr;
                size_t flat = obase + (size_t)q * 64 + d;
                float dn = s == 0 ? rs0[r] : rs1[r];
                oq[(flat >> 10) * 3072 + 1024 + (flat & 1023)] =
                    (bf16_t)(acc[s][nf][r] * dn);
            }
        }
    }
}

extern "C" void kernel_launch(void* const* d_in, const int* in_sizes, int n_in,
                              void* d_out, int out_size, void* d_ws, size_t ws_size,
                              hipStream_t stream) {
    const float* x     = (const float*)d_in[0];
    const float* gn_w  = (const float*)d_in[1];
    const float* gn_b  = (const float*)d_in[2];
    const float* w_qkv = (const float*)d_in[3];
    const float* b_qkv = (const float*)d_in[4];
    const float* w_out = (const float*)d_in[5];
    const float* b_out = (const float*)d_in[6];
    float* out = (float*)d_out;

    bf16_t* h      = (bf16_t*)d_ws;                  // 8 MiB; dead after gemm1 -> vfrag
    bf16_t* wqkv_b = h + (size_t)4096 * 1024;        // 6 MiB
    bf16_t* wout_b = wqkv_b + (size_t)3072 * 1024;   // 2 MiB
    bf16_t* qkvb   = wout_b + (size_t)1024 * 1024;   // 24 MiB: Q live; K band becomes O
    bf16_t* kfrag  = qkvb + (size_t)4096 * 3072;     // 8 MiB
    bf16_t* vfrag  = h;

    const int n1_4 = 3072 * 1024 / 4, ntot_4 = n1_4 + 1024 * 1024 / 4;
    cvt_bf16_kernel<<<(ntot_4 + 255) / 256, 256, 0, stream>>>(w_qkv, w_out, wqkv_b, wout_b, n1_4, ntot_4);
    groupnorm_kernel<<<128, 256, 0, stream>>>(x, gn_w, gn_b, h);
    gemm256_kernel<<<192, 512, 0, stream>>>(h, wqkv_b, b_qkv, qkvb, 4096, 3072, 1024);
    frag_prep_kernel<<<2048, 256, 0, stream>>>(qkvb, kfrag, vfrag);
    attn_kernel<<<512, 256, 0, stream>>>(qkvb, kfrag, vfrag, qkvb);
    gemm_nt_kernel<1, 128><<<256, 256, 0, stream>>>(qkvb + 1024, wout_b, b_out, (void*)out, x,
                                                    4096, 1024, 1024, 3072);
}

// Round 12
// 99.938 us; speedup vs baseline: 1.0604x; 1.0604x over previous
//
#include <hip/hip_runtime.h>

typedef __bf16 bf16_t;
typedef bf16_t bf16x8 __attribute__((ext_vector_type(8)));
typedef bf16_t bf16x4 __attribute__((ext_vector_type(4)));
typedef float f32x4 __attribute__((ext_vector_type(4)));

__device__ __forceinline__ void gload_lds16(const bf16_t* g, bf16_t* l) {
    __builtin_amdgcn_global_load_lds(
        (const __attribute__((address_space(1))) void*)g,
        (__attribute__((address_space(3))) void*)l, 16, 0, 0);
}

// ---------------- fused prep: GroupNorm (blocks 0..127) + weight cvt (blocks 128..) ----------------
__global__ __launch_bounds__(256, 2) void prep_kernel(const float* __restrict__ x,
        const float* __restrict__ gw, const float* __restrict__ gb, bf16_t* __restrict__ h,
        const float* __restrict__ in1, const float* __restrict__ in2,
        bf16_t* __restrict__ out1, bf16_t* __restrict__ out2, int n1_4, int ntot_4) {
    if (blockIdx.x >= 128) {
        int i = (blockIdx.x - 128) * 256 + threadIdx.x;
        if (i < ntot_4) {
            const float* in = (i < n1_4) ? in1 : in2;
            bf16_t* out = (i < n1_4) ? out1 : out2;
            int j = (i < n1_4) ? i : i - n1_4;
            float4 v = reinterpret_cast<const float4*>(in)[j];
            bf16x4 o;
            o[0] = (bf16_t)v.x; o[1] = (bf16_t)v.y; o[2] = (bf16_t)v.z; o[3] = (bf16_t)v.w;
            *reinterpret_cast<bf16x4*>(out + (size_t)j * 4) = o;
        }
        return;
    }
    int bg = blockIdx.x;
    int batch = bg >> 5, g = bg & 31;
    const float* xp = x + ((size_t)batch * 1024 + g * 32) * 1024;
    float4 xr[32];
    float s = 0.f, s2 = 0.f;
    #pragma unroll
    for (int i = 0; i < 32; ++i) {
        float4 v = reinterpret_cast<const float4*>(xp)[threadIdx.x + i * 256];
        xr[i] = v;
        s  += v.x + v.y + v.z + v.w;
        s2 += v.x*v.x + v.y*v.y + v.z*v.z + v.w*v.w;
    }
    #pragma unroll
    for (int o = 32; o >= 1; o >>= 1) {
        s  += __shfl_down(s, o, 64);
        s2 += __shfl_down(s2, o, 64);
    }
    __shared__ float ps[4], ps2[4];
    __shared__ float stat[2];
    if ((threadIdx.x & 63) == 0) { ps[threadIdx.x >> 6] = s; ps2[threadIdx.x >> 6] = s2; }
    __syncthreads();
    if (threadIdx.x == 0) {
        float S  = ps[0] + ps[1] + ps[2] + ps[3];
        float S2 = ps2[0] + ps2[1] + ps2[2] + ps2[3];
        float mu  = S * (1.f / 32768.f);
        float var = S2 * (1.f / 32768.f) - mu * mu;
        stat[0] = mu; stat[1] = rsqrtf(var + 1e-6f);
    }
    __syncthreads();
    float mu = stat[0], rs = stat[1];
    bf16_t* hp = h + ((size_t)batch * 1024 + g * 32) * 1024;
    #pragma unroll
    for (int i = 0; i < 32; ++i) {
        int idx = threadIdx.x + i * 256;
        int row = idx >> 8;
        float a = rs * gw[g * 32 + row];
        float b = gb[g * 32 + row] - mu * a;
        float4 v = xr[i];
        bf16x4 o;
        o[0] = (bf16_t)(v.x * a + b); o[1] = (bf16_t)(v.y * a + b);
        o[2] = (bf16_t)(v.z * a + b); o[3] = (bf16_t)(v.w * a + b);
        *reinterpret_cast<bf16x4*>(hp + (size_t)idx * 4) = o;
    }
}

// ---------------- 256x256 quadrant-phase bf16 GEMM (verified R7-R10): C = A @ W^T + bias ----------------
__global__ __launch_bounds__(512, 2) void gemm256_kernel(
        const bf16_t* __restrict__ A, const bf16_t* __restrict__ W,
        const float* __restrict__ bias, bf16_t* __restrict__ outp,
        int M, int N, int K) {
    __shared__ bf16_t As[2][2][128 * 64];
    __shared__ bf16_t Bs[2][2][128 * 64];
    int nbx = N >> 8;
    int cpx = gridDim.x >> 3;
    int bid = blockIdx.x;
    int tile = (bid & 7) * cpx + (bid >> 3);
    int bx = tile % nbx, by = tile / nbx;
    int m0 = by * 256, n0 = bx * 256;
    int t = threadIdx.x, l = t & 63, wid = t >> 6;
    int lr = l & 15, lg = l >> 4;
    int wm = (wid >> 2) * 128, wn = (wid & 3) * 64;
    int ah = wid >> 2;
    int bh = (wid & 3) >> 1;
    int bnl = wn & 64;

    int c0 = t, c1 = t + 512;
    int r0 = c0 >> 3, col0 = (((c0 & 7) ^ (r0 & 7)) << 3);
    int r1 = c1 >> 3, col1 = (((c1 & 7) ^ (r1 & 7)) << 3);

    f32x4 acc[8][4] = {};

#define STAGE_A(slot, hf, kt) { \
        const bf16_t* _s = A + (size_t)(m0 + (hf) * 128) * K + (kt) * 64; \
        gload_lds16(_s + (size_t)r0 * K + col0, &As[slot][hf][c0 * 8]); \
        gload_lds16(_s + (size_t)r1 * K + col1, &As[slot][hf][c1 * 8]); }
#define STAGE_B(slot, hf, kt) { \
        const bf16_t* _s = W + (size_t)(n0 + (hf) * 128) * K + (kt) * 64; \
        gload_lds16(_s + (size_t)r0 * K + col0, &Bs[slot][hf][c0 * 8]); \
        gload_lds16(_s + (size_t)r1 * K + col1, &Bs[slot][hf][c1 * 8]); }
#define LOAD_AF(mh) \
        _Pragma("unroll") \
        for (int i = 0; i < 4; ++i) { \
            int row = (mh) * 64 + i * 16 + lr; \
            _Pragma("unroll") \
            for (int kk = 0; kk < 2; ++kk) \
                afr[i][kk] = *reinterpret_cast<const bf16x8*>( \
                    &As[cur][ah][row * 64 + (((kk * 4 + lg) ^ (row & 7)) << 3)]); }
#define LOAD_BF(dst, nh) \
        _Pragma("unroll") \
        for (int j = 0; j < 2; ++j) { \
            int col = bnl + (nh) * 32 + j * 16 + lr; \
            _Pragma("unroll") \
            for (int kk = 0; kk < 2; ++kk) \
                dst[j][kk] = *reinterpret_cast<const bf16x8*>( \
                    &Bs[cur][bh][col * 64 + (((kk * 4 + lg) ^ (col & 7)) << 3)]); }
#define MFMA_Q(mh, nh, bfr) \
        __builtin_amdgcn_s_setprio(1); \
        _Pragma("unroll") \
        for (int i = 0; i < 4; ++i) \
            _Pragma("unroll") \
            for (int j = 0; j < 2; ++j) \
                _Pragma("unroll") \
                for (int kk = 0; kk < 2; ++kk) \
                    acc[(mh) * 4 + i][(nh) * 2 + j] = __builtin_amdgcn_mfma_f32_16x16x32_bf16( \
                        afr[i][kk], bfr[j][kk], acc[(mh) * 4 + i][(nh) * 2 + j], 0, 0, 0); \
        __builtin_amdgcn_s_setprio(0);

    STAGE_A(0, 0, 0) STAGE_B(0, 0, 0) STAGE_B(0, 1, 0) STAGE_A(0, 1, 0)
    asm volatile("s_waitcnt vmcnt(0)" ::: "memory");
    __builtin_amdgcn_s_barrier();

    const int NT = K >> 6;
    for (int kt = 0; kt < NT - 1; ++kt) {
        int cur = kt & 1, nxt = cur ^ 1;
        bf16x8 afr[4][2], bf0[2][2], bf1[2][2];
        LOAD_AF(0) LOAD_BF(bf0, 0)
        STAGE_A(nxt, 0, kt + 1)
        __builtin_amdgcn_s_barrier();
        MFMA_Q(0, 0, bf0)
        asm volatile("s_waitcnt vmcnt(4)" ::: "memory");
        __builtin_amdgcn_s_barrier();
        LOAD_BF(bf1, 1)
        STAGE_B(nxt, 0, kt + 1)
        __builtin_amdgcn_s_barrier();
        MFMA_Q(0, 1, bf1)
        asm volatile("s_waitcnt vmcnt(4)" ::: "memory");
        __builtin_amdgcn_s_barrier();
        LOAD_AF(1)
        STAGE_B(nxt, 1, kt + 1)
        __builtin_amdgcn_s_barrier();
        MFMA_Q(1, 1, bf1)
        __builtin_amdgcn_s_barrier();
        STAGE_A(nxt, 1, kt + 1)
        __builtin_amdgcn_s_barrier();
        MFMA_Q(1, 0, bf0)
        asm volatile("s_waitcnt vmcnt(4)" ::: "memory");
        __builtin_amdgcn_s_barrier();
    }
    {
        int cur = (NT - 1) & 1;
        asm volatile("s_waitcnt vmcnt(0)" ::: "memory");
        __builtin_amdgcn_s_barrier();
        bf16x8 afr[4][2], bf0[2][2], bf1[2][2];
        LOAD_AF(0) LOAD_BF(bf0, 0) LOAD_BF(bf1, 1)
        MFMA_Q(0, 0, bf0)
        MFMA_Q(0, 1, bf1)
        LOAD_AF(1)
        MFMA_Q(1, 1, bf1)
        MFMA_Q(1, 0, bf0)
    }

    #pragma unroll
    for (int mf = 0; mf < 8; ++mf) {
        #pragma unroll
        for (int r = 0; r < 4; ++r) {
            int row = m0 + wm + mf * 16 + lg * 4 + r;
            #pragma unroll
            for (int nf = 0; nf < 4; ++nf) {
                int col = n0 + wn + nf * 16 + lr;
                outp[(size_t)row * N + col] = (bf16_t)(acc[mf][nf][r] + bias[col]);
            }
        }
    }
#undef STAGE_A
#undef STAGE_B
#undef LOAD_AF
#undef LOAD_BF
#undef MFMA_Q
}

// ---------------- bf16 MFMA GEMM (m97 structure) with lda: C = A @ W^T (+bias[,+resid]) ----------------
template <int EPI, int BM>
__global__ __launch_bounds__(256) void gemm_nt_kernel(
        const bf16_t* __restrict__ A, const bf16_t* __restrict__ W,
        const float* __restrict__ bias, void* __restrict__ outp,
        const float* __restrict__ resid, int M, int N, int K, int lda) {
    constexpr int MF = BM / 32;
    __shared__ bf16_t As[BM * 64];
    __shared__ bf16_t Bs[128 * 64];
    int nbx = N >> 7;
    int cpx = gridDim.x >> 3;
    int bid = blockIdx.x;
    int tile = (bid & 7) * cpx + (bid >> 3);
    int bx = tile % nbx, by = tile / nbx;
    int m0 = by * BM, n0 = bx * 128;
    int t = threadIdx.x, l = t & 63, wid = t >> 6;
    int wm = (wid >> 1) * (BM / 2), wn = (wid & 1) * 64;
    int lr = l & 15, lg = l >> 4;

    f32x4 acc[MF][4] = {};
    for (int k0 = 0; k0 < K; k0 += 64) {
        #pragma unroll
        for (int i = 0; i < BM / 32; ++i) {
            int c = t + i * 256;
            int row = c >> 3, cc = c & 7;
            int col = (cc ^ (row & 7)) << 3;
            gload_lds16(A + (size_t)(m0 + row) * lda + k0 + col, &As[c * 8]);
        }
        #pragma unroll
        for (int i = 0; i < 4; ++i) {
            int c = t + i * 256;
            int row = c >> 3, cc = c & 7;
            int col = (cc ^ (row & 7)) << 3;
            gload_lds16(W + (size_t)(n0 + row) * K + k0 + col, &Bs[c * 8]);
        }
        __syncthreads();
        #pragma unroll
        for (int s = 0; s < 2; ++s) {
            int xo = ((s * 4 + lg) ^ (lr & 7)) << 3;
            bf16x8 af[MF], bfr[4];
            #pragma unroll
            for (int mf = 0; mf < MF; ++mf)
                af[mf] = *reinterpret_cast<const bf16x8*>(&As[(wm + mf * 16 + lr) * 64 + xo]);
            #pragma unroll
            for (int nf = 0; nf < 4; ++nf)
                bfr[nf] = *reinterpret_cast<const bf16x8*>(&Bs[(wn + nf * 16 + lr) * 64 + xo]);
            #pragma unroll
            for (int mf = 0; mf < MF; ++mf) {
                #pragma unroll
                for (int nf = 0; nf < 4; ++nf)
                    acc[mf][nf] = __builtin_amdgcn_mfma_f32_16x16x32_bf16(af[mf], bfr[nf], acc[mf][nf], 0, 0, 0);
            }
        }
        __syncthreads();
    }
    #pragma unroll
    for (int mf = 0; mf < MF; ++mf) {
        #pragma unroll
        for (int r = 0; r < 4; ++r) {
            int row = m0 + wm + mf * 16 + lg * 4 + r;
            #pragma unroll
            for (int nf = 0; nf < 4; ++nf) {
                int col = n0 + wn + nf * 16 + lr;
                float v = acc[mf][nf][r] + bias[col];
                if (EPI == 0) {
                    reinterpret_cast<bf16_t*>(outp)[(size_t)row * N + col] = (bf16_t)v;
                } else {
                    size_t idx = (size_t)row * N + col;
                    reinterpret_cast<float*>(outp)[idx] = v + resid[idx];
                }
            }
        }
    }
}

// ---------------- fragment prep: K/V of qkv -> MFMA-fragment-ordered buffers ----------------
__global__ __launch_bounds__(256) void frag_prep_kernel(const bf16_t* __restrict__ qkv,
                                                        bf16_t* __restrict__ kfrag,
                                                        bf16_t* __restrict__ vfrag) {
    __shared__ bf16_t vt[32 * 72];
    int t = threadIdx.x;
    int kt = blockIdx.x & 31, bh = blockIdx.x >> 5;
    int b = bh >> 4, hh = bh & 15;
    const bf16_t* kbase = qkv + ((size_t)b * 1024 + kt * 32) * 3072 + 1024 + hh * 64;
    const bf16_t* vbase = kbase + 1024;
    {
        int row = t >> 3, c = t & 7;
        bf16x8 v = *reinterpret_cast<const bf16x8*>(vbase + (size_t)row * 3072 + c * 8);
        *reinterpret_cast<bf16x8*>(&vt[row * 72 + c * 8]) = v;
    }
    {
        int f = (t >> 7) & 1, m = (t >> 6) & 1, l = t & 63;
        bf16x8 v = *reinterpret_cast<const bf16x8*>(
            kbase + (size_t)(f * 16 + (l & 15)) * 3072 + m * 32 + ((l >> 4) & 3) * 8);
        *reinterpret_cast<bf16x8*>(kfrag + ((size_t)bh * 32 + kt) * 2048 + t * 8) = v;
    }
    __syncthreads();
    {
        int nf = (t >> 6) & 3, l = t & 63;
        int d = nf * 16 + (l & 15);
        int lg = (l >> 4) & 3;
        bf16x8 o;
        #pragma unroll
        for (int j = 0; j < 8; ++j) {
            int kpos = lg * 8 + j;
            int kl = ((kpos & 4) << 2) | ((kpos & 24) >> 1) | (kpos & 3);
            o[j] = vt[kl * 72 + d];
        }
        *reinterpret_cast<bf16x8*>(vfrag + ((size_t)bh * 32 + kt) * 2048 + t * 8) = o;
    }
}

// ---------------- flash attention, v9 (verified ~16us): fragment-resident + lockstep L1 ----------------
__global__ __launch_bounds__(256, 2) void attn_kernel(const bf16_t* __restrict__ qkv,
                                                      const bf16_t* __restrict__ kfrag,
                                                      const bf16_t* __restrict__ vfrag,
                                                      bf16_t* __restrict__ oq) {
    int bid = blockIdx.x;
    int tile = (bid & 7) * 64 + (bid >> 3);
    int qt = tile & 7, bh = tile >> 3;
    int hh = bh & 15, bb = bh >> 4;
    int t = threadIdx.x, l = t & 63, wid = t >> 6;
    int lr = l & 15, lg = (l >> 4) & 3;

    bf16x8 qf[2][2];
    #pragma unroll
    for (int s = 0; s < 2; ++s) {
        int qrow = qt * 128 + wid * 32 + s * 16 + lr;
        const bf16_t* qp = qkv + ((size_t)bb * 1024 + qrow) * 3072 + hh * 64;
        bf16x8 q0 = *reinterpret_cast<const bf16x8*>(qp + lg * 8);
        bf16x8 q1 = *reinterpret_cast<const bf16x8*>(qp + 32 + lg * 8);
        #pragma unroll
        for (int j = 0; j < 8; ++j) {
            qf[s][0][j] = (bf16_t)((float)q0[j] * 0.02254211001f);
            qf[s][1][j] = (bf16_t)((float)q1[j] * 0.02254211001f);
        }
    }

    const bf16_t* kfb = kfrag + (size_t)bh * 65536 + l * 8;
    const bf16_t* vfb = vfrag + (size_t)bh * 65536 + l * 8;

    f32x4 acc[2][4] = {};
    float den0 = 0.f, den1 = 0.f;

    bf16x8 kA[4], vA[4], kB[4], vB[4];

#define LOADSET(kS, vS, tt) { \
        const bf16_t* _k = kfb + (tt) * 2048; \
        const bf16_t* _v = vfb + (tt) * 2048; \
        kS[0] = *reinterpret_cast<const bf16x8*>(_k); \
        kS[1] = *reinterpret_cast<const bf16x8*>(_k + 512); \
        kS[2] = *reinterpret_cast<const bf16x8*>(_k + 1024); \
        kS[3] = *reinterpret_cast<const bf16x8*>(_k + 1536); \
        vS[0] = *reinterpret_cast<const bf16x8*>(_v); \
        vS[1] = *reinterpret_cast<const bf16x8*>(_v + 512); \
        vS[2] = *reinterpret_cast<const bf16x8*>(_v + 1024); \
        vS[3] = *reinterpret_cast<const bf16x8*>(_v + 1536); }

#define EX(x) __builtin_amdgcn_exp2f(x)

#define COMPUTE(kS, vS) { \
        f32x4 z00 = {0.f,0.f,0.f,0.f}, z01 = {0.f,0.f,0.f,0.f}; \
        f32x4 z10 = {0.f,0.f,0.f,0.f}, z11 = {0.f,0.f,0.f,0.f}; \
        z00 = __builtin_amdgcn_mfma_f32_16x16x32_bf16(kS[0], qf[0][0], z00, 0, 0, 0); \
        z10 = __builtin_amdgcn_mfma_f32_16x16x32_bf16(kS[0], qf[1][0], z10, 0, 0, 0); \
        z01 = __builtin_amdgcn_mfma_f32_16x16x32_bf16(kS[2], qf[0][0], z01, 0, 0, 0); \
        z11 = __builtin_amdgcn_mfma_f32_16x16x32_bf16(kS[2], qf[1][0], z11, 0, 0, 0); \
        z00 = __builtin_amdgcn_mfma_f32_16x16x32_bf16(kS[1], qf[0][1], z00, 0, 0, 0); \
        z10 = __builtin_amdgcn_mfma_f32_16x16x32_bf16(kS[1], qf[1][1], z10, 0, 0, 0); \
        z01 = __builtin_amdgcn_mfma_f32_16x16x32_bf16(kS[3], qf[0][1], z01, 0, 0, 0); \
        z11 = __builtin_amdgcn_mfma_f32_16x16x32_bf16(kS[3], qf[1][1], z11, 0, 0, 0); \
        float a0 = EX(z00[0]), a1 = EX(z00[1]), a2 = EX(z00[2]), a3 = EX(z00[3]); \
        float a4 = EX(z01[0]), a5 = EX(z01[1]), a6 = EX(z01[2]), a7 = EX(z01[3]); \
        float b0 = EX(z10[0]), b1 = EX(z10[1]), b2 = EX(z10[2]), b3 = EX(z10[3]); \
        float b4 = EX(z11[0]), b5 = EX(z11[1]), b6 = EX(z11[2]), b7 = EX(z11[3]); \
        den0 += ((a0 + a1) + (a2 + a3)) + ((a4 + a5) + (a6 + a7)); \
        den1 += ((b0 + b1) + (b2 + b3)) + ((b4 + b5) + (b6 + b7)); \
        bf16x8 pa0, pa1; \
        pa0[0] = (bf16_t)a0; pa0[1] = (bf16_t)a1; pa0[2] = (bf16_t)a2; pa0[3] = (bf16_t)a3; \
        pa0[4] = (bf16_t)a4; pa0[5] = (bf16_t)a5; pa0[6] = (bf16_t)a6; pa0[7] = (bf16_t)a7; \
        pa1[0] = (bf16_t)b0; pa1[1] = (bf16_t)b1; pa1[2] = (bf16_t)b2; pa1[3] = (bf16_t)b3; \
        pa1[4] = (bf16_t)b4; pa1[5] = (bf16_t)b5; pa1[6] = (bf16_t)b6; pa1[7] = (bf16_t)b7; \
        acc[0][0] = __builtin_amdgcn_mfma_f32_16x16x32_bf16(pa0, vS[0], acc[0][0], 0, 0, 0); \
        acc[0][1] = __builtin_amdgcn_mfma_f32_16x16x32_bf16(pa0, vS[1], acc[0][1], 0, 0, 0); \
        acc[0][2] = __builtin_amdgcn_mfma_f32_16x16x32_bf16(pa0, vS[2], acc[0][2], 0, 0, 0); \
        acc[0][3] = __builtin_amdgcn_mfma_f32_16x16x32_bf16(pa0, vS[3], acc[0][3], 0, 0, 0); \
        acc[1][0] = __builtin_amdgcn_mfma_f32_16x16x32_bf16(pa1, vS[0], acc[1][0], 0, 0, 0); \
        acc[1][1] = __builtin_amdgcn_mfma_f32_16x16x32_bf16(pa1, vS[1], acc[1][1], 0, 0, 0); \
        acc[1][2] = __builtin_amdgcn_mfma_f32_16x16x32_bf16(pa1, vS[2], acc[1][2], 0, 0, 0); \
        acc[1][3] = __builtin_amdgcn_mfma_f32_16x16x32_bf16(pa1, vS[3], acc[1][3], 0, 0, 0); }

    LOADSET(kA, vA, 0)
    for (int kt = 0; kt < 32; kt += 2) {
        __builtin_amdgcn_s_barrier();   // lockstep -> L1 serves 3/4 of frag reads
        LOADSET(kB, vB, kt + 1)
        COMPUTE(kA, vA)
        if (kt + 2 < 32) LOADSET(kA, vA, kt + 2)
        COMPUTE(kB, vB)
    }
#undef LOADSET
#undef COMPUTE
#undef EX

    float rs0[4], rs1[4];
    {
        float v0 = den0, v1 = den1;
        v0 += __shfl_xor(v0, 16, 64);
        v0 += __shfl_xor(v0, 32, 64);
        v1 += __shfl_xor(v1, 16, 64);
        v1 += __shfl_xor(v1, 32, 64);
        #pragma unroll
        for (int r = 0; r < 4; ++r) {
            rs0[r] = 1.f / __shfl(v0, (l & 48) | (lg * 4 + r), 64);
            rs1[r] = 1.f / __shfl(v1, (l & 48) | (lg * 4 + r), 64);
        }
    }

    size_t obase = ((size_t)bh * 1024 + qt * 128 + wid * 32) * 64;
    #pragma unroll
    for (int s = 0; s < 2; ++s) {
        #pragma unroll
        for (int nf = 0; nf < 4; ++nf) {
            #pragma unroll
            for (int r = 0; r < 4; ++r) {
                int q = s * 16 + lg * 4 + r;
                int d = nf * 16 + lr;
                size_t flat = obase + (size_t)q * 64 + d;
                float dn = s == 0 ? rs0[r] : rs1[r];
                oq[(flat >> 10) * 3072 + 1024 + (flat & 1023)] =
                    (bf16_t)(acc[s][nf][r] * dn);
            }
        }
    }
}

extern "C" void kernel_launch(void* const* d_in, const int* in_sizes, int n_in,
                              void* d_out, int out_size, void* d_ws, size_t ws_size,
                              hipStream_t stream) {
    const float* x     = (const float*)d_in[0];
    const float* gn_w  = (const float*)d_in[1];
    const float* gn_b  = (const float*)d_in[2];
    const float* w_qkv = (const float*)d_in[3];
    const float* b_qkv = (const float*)d_in[4];
    const float* w_out = (const float*)d_in[5];
    const float* b_out = (const float*)d_in[6];
    float* out = (float*)d_out;

    bf16_t* h      = (bf16_t*)d_ws;                  // 8 MiB; dead after gemm1 -> vfrag
    bf16_t* wqkv_b = h + (size_t)4096 * 1024;        // 6 MiB
    bf16_t* wout_b = wqkv_b + (size_t)3072 * 1024;   // 2 MiB
    bf16_t* qkvb   = wout_b + (size_t)1024 * 1024;   // 24 MiB: Q live; K band becomes O
    bf16_t* kfrag  = qkvb + (size_t)4096 * 3072;     // 8 MiB
    bf16_t* vfrag  = h;

    const int n1_4 = 3072 * 1024 / 4, ntot_4 = n1_4 + 1024 * 1024 / 4;
    prep_kernel<<<128 + (ntot_4 + 255) / 256, 256, 0, stream>>>(
        x, gn_w, gn_b, h, w_qkv, w_out, wqkv_b, wout_b, n1_4, ntot_4);
    gemm256_kernel<<<192, 512, 0, stream>>>(h, wqkv_b, b_qkv, qkvb, 4096, 3072, 1024);
    frag_prep_kernel<<<2048, 256, 0, stream>>>(qkvb, kfrag, vfrag);
    attn_kernel<<<512, 256, 0, stream>>>(qkvb, kfrag, vfrag, qkvb);
    gemm_nt_kernel<1, 128><<<256, 256, 0, stream>>>(qkvb + 1024, wout_b, b_out, (void*)out, x,
                                                    4096, 1024, 1024, 3072);
}

// Round 13
// 92.636 us; speedup vs baseline: 1.1440x; 1.0788x over previous
//
#include <hip/hip_runtime.h>

typedef __bf16 bf16_t;
typedef bf16_t bf16x8 __attribute__((ext_vector_type(8)));
typedef bf16_t bf16x4 __attribute__((ext_vector_type(4)));
typedef float f32x4 __attribute__((ext_vector_type(4)));

__device__ __forceinline__ void gload_lds16(const bf16_t* g, bf16_t* l) {
    __builtin_amdgcn_global_load_lds(
        (const __attribute__((address_space(1))) void*)g,
        (__attribute__((address_space(3))) void*)l, 16, 0, 0);
}

// ---------------- fused prep: GroupNorm (blocks 0..127) + weight cvt (blocks 128..) ----------------
__global__ __launch_bounds__(256, 2) void prep_kernel(const float* __restrict__ x,
        const float* __restrict__ gw, const float* __restrict__ gb, bf16_t* __restrict__ h,
        const float* __restrict__ in1, const float* __restrict__ in2,
        bf16_t* __restrict__ out1, bf16_t* __restrict__ out2, int n1_4, int ntot_4) {
    if (blockIdx.x >= 128) {
        int i = (blockIdx.x - 128) * 256 + threadIdx.x;
        if (i < ntot_4) {
            const float* in = (i < n1_4) ? in1 : in2;
            bf16_t* out = (i < n1_4) ? out1 : out2;
            int j = (i < n1_4) ? i : i - n1_4;
            float4 v = reinterpret_cast<const float4*>(in)[j];
            bf16x4 o;
            o[0] = (bf16_t)v.x; o[1] = (bf16_t)v.y; o[2] = (bf16_t)v.z; o[3] = (bf16_t)v.w;
            *reinterpret_cast<bf16x4*>(out + (size_t)j * 4) = o;
        }
        return;
    }
    int bg = blockIdx.x;
    int batch = bg >> 5, g = bg & 31;
    const float* xp = x + ((size_t)batch * 1024 + g * 32) * 1024;
    float4 xr[32];
    float s = 0.f, s2 = 0.f;
    #pragma unroll
    for (int i = 0; i < 32; ++i) {
        float4 v = reinterpret_cast<const float4*>(xp)[threadIdx.x + i * 256];
        xr[i] = v;
        s  += v.x + v.y + v.z + v.w;
        s2 += v.x*v.x + v.y*v.y + v.z*v.z + v.w*v.w;
    }
    #pragma unroll
    for (int o = 32; o >= 1; o >>= 1) {
        s  += __shfl_down(s, o, 64);
        s2 += __shfl_down(s2, o, 64);
    }
    __shared__ float ps[4], ps2[4];
    __shared__ float stat[2];
    if ((threadIdx.x & 63) == 0) { ps[threadIdx.x >> 6] = s; ps2[threadIdx.x >> 6] = s2; }
    __syncthreads();
    if (threadIdx.x == 0) {
        float S  = ps[0] + ps[1] + ps[2] + ps[3];
        float S2 = ps2[0] + ps2[1] + ps2[2] + ps2[3];
        float mu  = S * (1.f / 32768.f);
        float var = S2 * (1.f / 32768.f) - mu * mu;
        stat[0] = mu; stat[1] = rsqrtf(var + 1e-6f);
    }
    __syncthreads();
    float mu = stat[0], rs = stat[1];
    bf16_t* hp = h + ((size_t)batch * 1024 + g * 32) * 1024;
    #pragma unroll
    for (int i = 0; i < 32; ++i) {
        int idx = threadIdx.x + i * 256;
        int row = idx >> 8;
        float a = rs * gw[g * 32 + row];
        float b = gb[g * 32 + row] - mu * a;
        float4 v = xr[i];
        bf16x4 o;
        o[0] = (bf16_t)(v.x * a + b); o[1] = (bf16_t)(v.y * a + b);
        o[2] = (bf16_t)(v.z * a + b); o[3] = (bf16_t)(v.w * a + b);
        *reinterpret_cast<bf16x4*>(hp + (size_t)idx * 4) = o;
    }
}

// ---------------- 256x192 quadrant-phase bf16 GEMM: C = A @ W^T + bias ----------------
// Iso-structural port of the verified R7 quadrant schedule to BN=192:
// grid 16x16 = 256 blocks -> 100% CU fill (was 192/256 = 75%).
// 8 waves as 4M x 2N (each wave 64x96, acc 4x6). A: 2 halves of 128 rows (2 loads/thr).
// B: 3 thirds of 64 rows (1 load/thr each) -> uniform 7 loads/thread/iter.
// Same phase order, same vmcnt(4) cadence, same peeled tail as R7.
__global__ __launch_bounds__(512, 2) void gemm256_kernel(
        const bf16_t* __restrict__ A, const bf16_t* __restrict__ W,
        const float* __restrict__ bias, bf16_t* __restrict__ outp,
        int M, int N, int K) {
    __shared__ bf16_t As[2][2][128 * 64];
    __shared__ bf16_t Bs[2][3][64 * 64];
    int cpx = gridDim.x >> 3;
    int bid = blockIdx.x;
    int tile = (bid & 7) * cpx + (bid >> 3);
    int bx = tile & 15, by = tile >> 4;
    int m0 = by * 256, n0 = bx * 192;
    int t = threadIdx.x, l = t & 63, wid = t >> 6;
    int lr = l & 15, lg = l >> 4;
    int gm = (wid >> 2) * 128 + ((wid >> 1) & 1) * 64;  // wave M offset in tile
    int gn = (wid & 1) * 96;                            // wave N offset in tile
    int ah = wid >> 2;                                  // A half this wave reads
    int aml = ((wid >> 1) & 1) * 64;                    // local row base within A half

    int c0 = t, c1 = t + 512;
    int r0 = c0 >> 3, col0 = (((c0 & 7) ^ (r0 & 7)) << 3);
    int r1 = c1 >> 3, col1 = (((c1 & 7) ^ (r1 & 7)) << 3);

    f32x4 acc[4][6] = {};

#define STAGE_A(slot, hf, kt) { \
        const bf16_t* _s = A + (size_t)(m0 + (hf) * 128) * K + (kt) * 64; \
        gload_lds16(_s + (size_t)r0 * K + col0, &As[slot][hf][c0 * 8]); \
        gload_lds16(_s + (size_t)r1 * K + col1, &As[slot][hf][c1 * 8]); }
#define STAGE_B3(slot, th, kt) { \
        const bf16_t* _s = W + (size_t)(n0 + (th) * 64) * K + (kt) * 64; \
        gload_lds16(_s + (size_t)r0 * K + col0, &Bs[slot][th][c0 * 8]); }
#define LOAD_AF(slot, mq) \
        _Pragma("unroll") \
        for (int i = 0; i < 2; ++i) { \
            int row = aml + (mq) * 32 + i * 16 + lr; \
            _Pragma("unroll") \
            for (int kk = 0; kk < 2; ++kk) \
                afr[i][kk] = *reinterpret_cast<const bf16x8*>( \
                    &As[slot][ah][row * 64 + (((kk * 4 + lg) ^ (row & 7)) << 3)]); }
#define LOAD_BF(slot, dst, nq) \
        _Pragma("unroll") \
        for (int j = 0; j < 3; ++j) { \
            int col = gn + (nq) * 48 + j * 16 + lr; \
            _Pragma("unroll") \
            for (int kk = 0; kk < 2; ++kk) \
                dst[j][kk] = *reinterpret_cast<const bf16x8*>( \
                    &Bs[slot][col >> 6][(col & 63) * 64 + (((kk * 4 + lg) ^ (col & 7)) << 3)]); }
#define MFMA_Q(mq, nq, bfr) \
        __builtin_amdgcn_s_setprio(1); \
        _Pragma("unroll") \
        for (int i = 0; i < 2; ++i) \
            _Pragma("unroll") \
            for (int j = 0; j < 3; ++j) \
                _Pragma("unroll") \
                for (int kk = 0; kk < 2; ++kk) \
                    acc[(mq) * 2 + i][(nq) * 3 + j] = __builtin_amdgcn_mfma_f32_16x16x32_bf16( \
                        afr[i][kk], bfr[j][kk], acc[(mq) * 2 + i][(nq) * 3 + j], 0, 0, 0); \
        __builtin_amdgcn_s_setprio(0);

    // prologue: stage tile 0 fully
    STAGE_A(0, 0, 0) STAGE_B3(0, 0, 0) STAGE_B3(0, 1, 0) STAGE_B3(0, 2, 0) STAGE_A(0, 1, 0)
    asm volatile("s_waitcnt vmcnt(0)" ::: "memory");
    __builtin_amdgcn_s_barrier();

    const int NT = K >> 6;
    for (int kt = 0; kt < NT - 1; ++kt) {
        int cur = kt & 1, nxt = cur ^ 1;
        bf16x8 afr[2][2], bf0[3][2], bf1[3][2];
        // P1: quadrant (m0,n0); stage next A0
        LOAD_AF(cur, 0) LOAD_BF(cur, bf0, 0)
        STAGE_A(nxt, 0, kt + 1)
        __builtin_amdgcn_s_barrier();
        MFMA_Q(0, 0, bf0)
        asm volatile("s_waitcnt vmcnt(4)" ::: "memory");
        __builtin_amdgcn_s_barrier();
        // P2: (m0,n1); stage next B0,B1
        LOAD_BF(cur, bf1, 1)
        STAGE_B3(nxt, 0, kt + 1)
        STAGE_B3(nxt, 1, kt + 1)
        __builtin_amdgcn_s_barrier();
        MFMA_Q(0, 1, bf1)
        asm volatile("s_waitcnt vmcnt(4)" ::: "memory");
        __builtin_amdgcn_s_barrier();
        // P3: (m1,n1); stage next B2
        LOAD_AF(cur, 1)
        STAGE_B3(nxt, 2, kt + 1)
        __builtin_amdgcn_s_barrier();
        MFMA_Q(1, 1, bf1)
        __builtin_amdgcn_s_barrier();
        // P4: (m1,n0) with held bf0; stage next A1
        STAGE_A(nxt, 1, kt + 1)
        __builtin_amdgcn_s_barrier();
        MFMA_Q(1, 0, bf0)
        asm volatile("s_waitcnt vmcnt(4)" ::: "memory");
        __builtin_amdgcn_s_barrier();
    }
    {   // peeled last tile
        int cur = (NT - 1) & 1;
        asm volatile("s_waitcnt vmcnt(0)" ::: "memory");
        __builtin_amdgcn_s_barrier();
        bf16x8 afr[2][2], bf0[3][2], bf1[3][2];
        LOAD_AF(cur, 0) LOAD_BF(cur, bf0, 0) LOAD_BF(cur, bf1, 1)
        MFMA_Q(0, 0, bf0)
        MFMA_Q(0, 1, bf1)
        LOAD_AF(cur, 1)
        MFMA_Q(1, 1, bf1)
        MFMA_Q(1, 0, bf0)
    }

    #pragma unroll
    for (int mf = 0; mf < 4; ++mf) {
        #pragma unroll
        for (int r = 0; r < 4; ++r) {
            int row = m0 + gm + mf * 16 + lg * 4 + r;
            #pragma unroll
            for (int nf = 0; nf < 6; ++nf) {
                int col = n0 + gn + nf * 16 + lr;
                outp[(size_t)row * N + col] = (bf16_t)(acc[mf][nf][r] + bias[col]);
            }
        }
    }
#undef STAGE_A
#undef STAGE_B3
#undef LOAD_AF
#undef LOAD_BF
#undef MFMA_Q
}

// ---------------- bf16 MFMA GEMM (m97 structure) with lda: C = A @ W^T (+bias[,+resid]) ----------------
template <int EPI, int BM>
__global__ __launch_bounds__(256) void gemm_nt_kernel(
        const bf16_t* __restrict__ A, const bf16_t* __restrict__ W,
        const float* __restrict__ bias, void* __restrict__ outp,
        const float* __restrict__ resid, int M, int N, int K, int lda) {
    constexpr int MF = BM / 32;
    __shared__ bf16_t As[BM * 64];
    __shared__ bf16_t Bs[128 * 64];
    int nbx = N >> 7;
    int cpx = gridDim.x >> 3;
    int bid = blockIdx.x;
    int tile = (bid & 7) * cpx + (bid >> 3);
    int bx = tile % nbx, by = tile / nbx;
    int m0 = by * BM, n0 = bx * 128;
    int t = threadIdx.x, l = t & 63, wid = t >> 6;
    int wm = (wid >> 1) * (BM / 2), wn = (wid & 1) * 64;
    int lr = l & 15, lg = l >> 4;

    f32x4 acc[MF][4] = {};
    for (int k0 = 0; k0 < K; k0 += 64) {
        #pragma unroll
        for (int i = 0; i < BM / 32; ++i) {
            int c = t + i * 256;
            int row = c >> 3, cc = c & 7;
            int col = (cc ^ (row & 7)) << 3;
            gload_lds16(A + (size_t)(m0 + row) * lda + k0 + col, &As[c * 8]);
        }
        #pragma unroll
        for (int i = 0; i < 4; ++i) {
            int c = t + i * 256;
            int row = c >> 3, cc = c & 7;
            int col = (cc ^ (row & 7)) << 3;
            gload_lds16(W + (size_t)(n0 + row) * K + k0 + col, &Bs[c * 8]);
        }
        __syncthreads();
        #pragma unroll
        for (int s = 0; s < 2; ++s) {
            int xo = ((s * 4 + lg) ^ (lr & 7)) << 3;
            bf16x8 af[MF], bfr[4];
            #pragma unroll
            for (int mf = 0; mf < MF; ++mf)
                af[mf] = *reinterpret_cast<const bf16x8*>(&As[(wm + mf * 16 + lr) * 64 + xo]);
            #pragma unroll
            for (int nf = 0; nf < 4; ++nf)
                bfr[nf] = *reinterpret_cast<const bf16x8*>(&Bs[(wn + nf * 16 + lr) * 64 + xo]);
            #pragma unroll
            for (int mf = 0; mf < MF; ++mf) {
                #pragma unroll
                for (int nf = 0; nf < 4; ++nf)
                    acc[mf][nf] = __builtin_amdgcn_mfma_f32_16x16x32_bf16(af[mf], bfr[nf], acc[mf][nf], 0, 0, 0);
            }
        }
        __syncthreads();
    }
    #pragma unroll
    for (int mf = 0; mf < MF; ++mf) {
        #pragma unroll
        for (int r = 0; r < 4; ++r) {
            int row = m0 + wm + mf * 16 + lg * 4 + r;
            #pragma unroll
            for (int nf = 0; nf < 4; ++nf) {
                int col = n0 + wn + nf * 16 + lr;
                float v = acc[mf][nf][r] + bias[col];
                if (EPI == 0) {
                    reinterpret_cast<bf16_t*>(outp)[(size_t)row * N + col] = (bf16_t)v;
                } else {
                    size_t idx = (size_t)row * N + col;
                    reinterpret_cast<float*>(outp)[idx] = v + resid[idx];
                }
            }
        }
    }
}

// ---------------- fragment prep: K/V of qkv -> MFMA-fragment-ordered buffers ----------------
__global__ __launch_bounds__(256) void frag_prep_kernel(const bf16_t* __restrict__ qkv,
                                                        bf16_t* __restrict__ kfrag,
                                                        bf16_t* __restrict__ vfrag) {
    __shared__ bf16_t vt[32 * 72];
    int t = threadIdx.x;
    int kt = blockIdx.x & 31, bh = blockIdx.x >> 5;
    int b = bh >> 4, hh = bh & 15;
    const bf16_t* kbase = qkv + ((size_t)b * 1024 + kt * 32) * 3072 + 1024 + hh * 64;
    const bf16_t* vbase = kbase + 1024;
    {
        int row = t >> 3, c = t & 7;
        bf16x8 v = *reinterpret_cast<const bf16x8*>(vbase + (size_t)row * 3072 + c * 8);
        *reinterpret_cast<bf16x8*>(&vt[row * 72 + c * 8]) = v;
    }
    {
        int f = (t >> 7) & 1, m = (t >> 6) & 1, l = t & 63;
        bf16x8 v = *reinterpret_cast<const bf16x8*>(
            kbase + (size_t)(f * 16 + (l & 15)) * 3072 + m * 32 + ((l >> 4) & 3) * 8);
        *reinterpret_cast<bf16x8*>(kfrag + ((size_t)bh * 32 + kt) * 2048 + t * 8) = v;
    }
    __syncthreads();
    {
        int nf = (t >> 6) & 3, l = t & 63;
        int d = nf * 16 + (l & 15);
        int lg = (l >> 4) & 3;
        bf16x8 o;
        #pragma unroll
        for (int j = 0; j < 8; ++j) {
            int kpos = lg * 8 + j;
            int kl = ((kpos & 4) << 2) | ((kpos & 24) >> 1) | (kpos & 3);
            o[j] = vt[kl * 72 + d];
        }
        *reinterpret_cast<bf16x8*>(vfrag + ((size_t)bh * 32 + kt) * 2048 + t * 8) = o;
    }
}

// ---------------- flash attention, v9 (verified ~16us): fragment-resident + lockstep L1 ----------------
__global__ __launch_bounds__(256, 2) void attn_kernel(const bf16_t* __restrict__ qkv,
                                                      const bf16_t* __restrict__ kfrag,
                                                      const bf16_t* __restrict__ vfrag,
                                                      bf16_t* __restrict__ oq) {
    int bid = blockIdx.x;
    int tile = (bid & 7) * 64 + (bid >> 3);
    int qt = tile & 7, bh = tile >> 3;
    int hh = bh & 15, bb = bh >> 4;
    int t = threadIdx.x, l = t & 63, wid = t >> 6;
    int lr = l & 15, lg = (l >> 4) & 3;

    bf16x8 qf[2][2];
    #pragma unroll
    for (int s = 0; s < 2; ++s) {
        int qrow = qt * 128 + wid * 32 + s * 16 + lr;
        const bf16_t* qp = qkv + ((size_t)bb * 1024 + qrow) * 3072 + hh * 64;
        bf16x8 q0 = *reinterpret_cast<const bf16x8*>(qp + lg * 8);
        bf16x8 q1 = *reinterpret_cast<const bf16x8*>(qp + 32 + lg * 8);
        #pragma unroll
        for (int j = 0; j < 8; ++j) {
            qf[s][0][j] = (bf16_t)((float)q0[j] * 0.02254211001f);
            qf[s][1][j] = (bf16_t)((float)q1[j] * 0.02254211001f);
        }
    }

    const bf16_t* kfb = kfrag + (size_t)bh * 65536 + l * 8;
    const bf16_t* vfb = vfrag + (size_t)bh * 65536 + l * 8;

    f32x4 acc[2][4] = {};
    float den0 = 0.f, den1 = 0.f;

    bf16x8 kA[4], vA[4], kB[4], vB[4];

#define LOADSET(kS, vS, tt) { \
        const bf16_t* _k = kfb + (tt) * 2048; \
        const bf16_t* _v = vfb + (tt) * 2048; \
        kS[0] = *reinterpret_cast<const bf16x8*>(_k); \
        kS[1] = *reinterpret_cast<const bf16x8*>(_k + 512); \
        kS[2] = *reinterpret_cast<const bf16x8*>(_k + 1024); \
        kS[3] = *reinterpret_cast<const bf16x8*>(_k + 1536); \
        vS[0] = *reinterpret_cast<const bf16x8*>(_v); \
        vS[1] = *reinterpret_cast<const bf16x8*>(_v + 512); \
        vS[2] = *reinterpret_cast<const bf16x8*>(_v + 1024); \
        vS[3] = *reinterpret_cast<const bf16x8*>(_v + 1536); }

#define EX(x) __builtin_amdgcn_exp2f(x)

#define COMPUTE(kS, vS) { \
        f32x4 z00 = {0.f,0.f,0.f,0.f}, z01 = {0.f,0.f,0.f,0.f}; \
        f32x4 z10 = {0.f,0.f,0.f,0.f}, z11 = {0.f,0.f,0.f,0.f}; \
        z00 = __builtin_amdgcn_mfma_f32_16x16x32_bf16(kS[0], qf[0][0], z00, 0, 0, 0); \
        z10 = __builtin_amdgcn_mfma_f32_16x16x32_bf16(kS[0], qf[1][0], z10, 0, 0, 0); \
        z01 = __builtin_amdgcn_mfma_f32_16x16x32_bf16(kS[2], qf[0][0], z01, 0, 0, 0); \
        z11 = __builtin_amdgcn_mfma_f32_16x16x32_bf16(kS[2], qf[1][0], z11, 0, 0, 0); \
        z00 = __builtin_amdgcn_mfma_f32_16x16x32_bf16(kS[1], qf[0][1], z00, 0, 0, 0); \
        z10 = __builtin_amdgcn_mfma_f32_16x16x32_bf16(kS[1], qf[1][1], z10, 0, 0, 0); \
        z01 = __builtin_amdgcn_mfma_f32_16x16x32_bf16(kS[3], qf[0][1], z01, 0, 0, 0); \
        z11 = __builtin_amdgcn_mfma_f32_16x16x32_bf16(kS[3], qf[1][1], z11, 0, 0, 0); \
        float a0 = EX(z00[0]), a1 = EX(z00[1]), a2 = EX(z00[2]), a3 = EX(z00[3]); \
        float a4 = EX(z01[0]), a5 = EX(z01[1]), a6 = EX(z01[2]), a7 = EX(z01[3]); \
        float b0 = EX(z10[0]), b1 = EX(z10[1]), b2 = EX(z10[2]), b3 = EX(z10[3]); \
        float b4 = EX(z11[0]), b5 = EX(z11[1]), b6 = EX(z11[2]), b7 = EX(z11[3]); \
        den0 += ((a0 + a1) + (a2 + a3)) + ((a4 + a5) + (a6 + a7)); \
        den1 += ((b0 + b1) + (b2 + b3)) + ((b4 + b5) + (b6 + b7)); \
        bf16x8 pa0, pa1; \
        pa0[0] = (bf16_t)a0; pa0[1] = (bf16_t)a1; pa0[2] = (bf16_t)a2; pa0[3] = (bf16_t)a3; \
        pa0[4] = (bf16_t)a4; pa0[5] = (bf16_t)a5; pa0[6] = (bf16_t)a6; pa0[7] = (bf16_t)a7; \
        pa1[0] = (bf16_t)b0; pa1[1] = (bf16_t)b1; pa1[2] = (bf16_t)b2; pa1[3] = (bf16_t)b3; \
        pa1[4] = (bf16_t)b4; pa1[5] = (bf16_t)b5; pa1[6] = (bf16_t)b6; pa1[7] = (bf16_t)b7; \
        acc[0][0] = __builtin_amdgcn_mfma_f32_16x16x32_bf16(pa0, vS[0], acc[0][0], 0, 0, 0); \
        acc[0][1] = __builtin_amdgcn_mfma_f32_16x16x32_bf16(pa0, vS[1], acc[0][1], 0, 0, 0); \
        acc[0][2] = __builtin_amdgcn_mfma_f32_16x16x32_bf16(pa0, vS[2], acc[0][2], 0, 0, 0); \
        acc[0][3] = __builtin_amdgcn_mfma_f32_16x16x32_bf16(pa0, vS[3], acc[0][3], 0, 0, 0); \
        acc[1][0] = __builtin_amdgcn_mfma_f32_16x16x32_bf16(pa1, vS[0], acc[1][0], 0, 0, 0); \
        acc[1][1] = __builtin_amdgcn_mfma_f32_16x16x32_bf16(pa1, vS[1], acc[1][1], 0, 0, 0); \
        acc[1][2] = __builtin_amdgcn_mfma_f32_16x16x32_bf16(pa1, vS[2], acc[1][2], 0, 0, 0); \
        acc[1][3] = __builtin_amdgcn_mfma_f32_16x16x32_bf16(pa1, vS[3], acc[1][3], 0, 0, 0); }

    LOADSET(kA, vA, 0)
    for (int kt = 0; kt < 32; kt += 2) {
        __builtin_amdgcn_s_barrier();   // lockstep -> L1 serves 3/4 of frag reads
        LOADSET(kB, vB, kt + 1)
        COMPUTE(kA, vA)
        if (kt + 2 < 32) LOADSET(kA, vA, kt + 2)
        COMPUTE(kB, vB)
    }
#undef LOADSET
#undef COMPUTE
#undef EX

    float rs0[4], rs1[4];
    {
        float v0 = den0, v1 = den1;
        v0 += __shfl_xor(v0, 16, 64);
        v0 += __shfl_xor(v0, 32, 64);
        v1 += __shfl_xor(v1, 16, 64);
        v1 += __shfl_xor(v1, 32, 64);
        #pragma unroll
        for (int r = 0; r < 4; ++r) {
            rs0[r] = 1.f / __shfl(v0, (l & 48) | (lg * 4 + r), 64);
            rs1[r] = 1.f / __shfl(v1, (l & 48) | (lg * 4 + r), 64);
        }
    }

    size_t obase = ((size_t)bh * 1024 + qt * 128 + wid * 32) * 64;
    #pragma unroll
    for (int s = 0; s < 2; ++s) {
        #pragma unroll
        for (int nf = 0; nf < 4; ++nf) {
            #pragma unroll
            for (int r = 0; r < 4; ++r) {
                int q = s * 16 + lg * 4 + r;
                int d = nf * 16 + lr;
                size_t flat = obase + (size_t)q * 64 + d;
                float dn = s == 0 ? rs0[r] : rs1[r];
                oq[(flat >> 10) * 3072 + 1024 + (flat & 1023)] =
                    (bf16_t)(acc[s][nf][r] * dn);
            }
        }
    }
}

extern "C" void kernel_launch(void* const* d_in, const int* in_sizes, int n_in,
                              void* d_out, int out_size, void* d_ws, size_t ws_size,
                              hipStream_t stream) {
    const float* x     = (const float*)d_in[0];
    const float* gn_w  = (const float*)d_in[1];
    const float* gn_b  = (const float*)d_in[2];
    const float* w_qkv = (const float*)d_in[3];
    const float* b_qkv = (const float*)d_in[4];
    const float* w_out = (const float*)d_in[5];
    const float* b_out = (const float*)d_in[6];
    float* out = (float*)d_out;

    bf16_t* h      = (bf16_t*)d_ws;                  // 8 MiB; dead after gemm1 -> vfrag
    bf16_t* wqkv_b = h + (size_t)4096 * 1024;        // 6 MiB
    bf16_t* wout_b = wqkv_b + (size_t)3072 * 1024;   // 2 MiB
    bf16_t* qkvb   = wout_b + (size_t)1024 * 1024;   // 24 MiB: Q live; K band becomes O
    bf16_t* kfrag  = qkvb + (size_t)4096 * 3072;     // 8 MiB
    bf16_t* vfrag  = h;

    const int n1_4 = 3072 * 1024 / 4, ntot_4 = n1_4 + 1024 * 1024 / 4;
    prep_kernel<<<128 + (ntot_4 + 255) / 256, 256, 0, stream>>>(
        x, gn_w, gn_b, h, w_qkv, w_out, wqkv_b, wout_b, n1_4, ntot_4);
    gemm256_kernel<<<256, 512, 0, stream>>>(h, wqkv_b, b_qkv, qkvb, 4096, 3072, 1024);
    frag_prep_kernel<<<2048, 256, 0, stream>>>(qkvb, kfrag, vfrag);
    attn_kernel<<<512, 256, 0, stream>>>(qkvb, kfrag, vfrag, qkvb);
    gemm_nt_kernel<1, 64><<<512, 256, 0, stream>>>(qkvb + 1024, wout_b, b_out, (void*)out, x,
                                                   4096, 1024, 1024, 3072);
}